// Round 1
// baseline (797.636 us; speedup 1.0000x reference)
//
#include <hip/hip_runtime.h>
#include <hip/hip_bf16.h>

#define DE 1024
#define DM 64
#define DC 128
#define DX 1152      // DE+DC
#define NB 4
#define NN 4096
#define NT 16384     // NB*NN

typedef _Float16 f16;
typedef _Float16 f16x4 __attribute__((ext_vector_type(4)));
typedef _Float16 f16x8 __attribute__((ext_vector_type(8)));
typedef float f32x4 __attribute__((ext_vector_type(4)));

__device__ __forceinline__ void g2l16(const void* g, void* l) {
  __builtin_amdgcn_global_load_lds(
      (const __attribute__((address_space(1))) unsigned int*)(unsigned long long)g,
      (__attribute__((address_space(3))) unsigned int*)(unsigned int)(unsigned long long)l,
      16, 0, 0);
}

// ---------------- prep kernels ----------------
__global__ void build_x_kernel(const float* __restrict__ e, const float* __restrict__ c,
                               f16* __restrict__ Xb) {
  const int total = NT * DX / 4;
  for (int i = blockIdx.x * blockDim.x + threadIdx.x; i < total; i += gridDim.x * blockDim.x) {
    int idx = i * 4;
    int r = idx / DX, col = idx - r * DX;
    float4 v;
    if (col < DE) v = *(const float4*)(e + (long)r * DE + col);
    else          v = *(const float4*)(c + (long)r * DC + (col - DE));
    f16x4 o = { (f16)v.x, (f16)v.y, (f16)v.z, (f16)v.w };
    *(f16x4*)(Xb + (long)idx) = o;
  }
}

__global__ void conv_f16_kernel(const float* __restrict__ in, f16* __restrict__ out, int total4) {
  for (int i = blockIdx.x * blockDim.x + threadIdx.x; i < total4; i += gridDim.x * blockDim.x) {
    float4 v = *(const float4*)(in + (long)i * 4);
    f16x4 o = { (f16)v.x, (f16)v.y, (f16)v.z, (f16)v.w };
    *(f16x4*)(out + (long)i * 4) = o;
  }
}

// in [DX][DE] f32  ->  out [DE][DX] f16   (LDS-tiled transpose)
__global__ void transpose_w_kernel(const float* __restrict__ in, f16* __restrict__ out) {
  __shared__ float tile[32][33];
  int c0 = blockIdx.x * 32, r0 = blockIdx.y * 32;
  int x = threadIdx.x, y = threadIdx.y;   // block (32,8)
#pragma unroll
  for (int i = 0; i < 4; ++i)
    tile[y + 8 * i][x] = in[(long)(r0 + y + 8 * i) * DE + (c0 + x)];
  __syncthreads();
#pragma unroll
  for (int i = 0; i < 4; ++i)
    out[(long)(c0 + y + 8 * i) * DX + (r0 + x)] = (f16)tile[x][y + 8 * i];
}

// ---------------- shared GEMM core (m97 structure) ----------------
// C[128x128] += A[128xK] * B[128xK]^T   (both operands row-major [rows][K])
// 256 threads = 4 waves in 2x2; per-wave 64x64 via 4x4 of 16x16x32 MFMA.
__device__ __forceinline__ void mm_loop(const f16* __restrict__ A, const f16* __restrict__ B,
                                        int lda, int ldb, int K,
                                        f16* lA, f16* lB, f32x4 (&acc)[4][4]) {
  const int t = threadIdx.x;
  const int lane = t & 63;
  const int wid = t >> 6;
  const int wr = (wid >> 1) * 64, wc = (wid & 1) * 64;
  const int fr = lane & 15, fq = lane >> 4;
  for (int k0 = 0; k0 < K; k0 += 32) {
    __syncthreads();
#pragma unroll
    for (int it = 0; it < 2; ++it) {
      int byteoff = it * 4096 + t * 16;
      int row = byteoff >> 6;          // 64 B per 32-elem row
      int ke = (byteoff & 63) >> 1;    // f16 elems within row
      g2l16(A + (long)row * lda + k0 + ke, lA + (byteoff >> 1));
      g2l16(B + (long)row * ldb + k0 + ke, lB + (byteoff >> 1));
    }
    __syncthreads();
    f16x8 af[4], bfr[4];
#pragma unroll
    for (int i = 0; i < 4; ++i) {
      af[i]  = *(const f16x8*)(lA + (wr + i * 16 + fr) * 32 + fq * 8);
      bfr[i] = *(const f16x8*)(lB + (wc + i * 16 + fr) * 32 + fq * 8);
    }
#pragma unroll
    for (int m = 0; m < 4; ++m)
#pragma unroll
      for (int n = 0; n < 4; ++n)
        acc[m][n] = __builtin_amdgcn_mfma_f32_16x16x32_f16(af[m], bfr[n], acc[m][n], 0, 0, 0);
  }
}

#define GEMM_PRE()                                                    \
  __shared__ __attribute__((aligned(16))) f16 lA[128 * 32], lB[128 * 32]; \
  f32x4 acc[4][4];                                                    \
  _Pragma("unroll") for (int m = 0; m < 4; ++m)                       \
  _Pragma("unroll") for (int n = 0; n < 4; ++n)                       \
      acc[m][n] = (f32x4){0.f, 0.f, 0.f, 0.f};

#define EPI_IDX()                                                     \
  const int lane = threadIdx.x & 63, wid = threadIdx.x >> 6;          \
  const int wr = (wid >> 1) * 64, wc = (wid & 1) * 64;                \
  const int fr = lane & 15, fq = lane >> 4;

// q,k projection: M=16384 (tokens), N=2048 (q|k), K=1152
__global__ __launch_bounds__(256) void gemm_qk_kernel(
    const f16* __restrict__ Xb, const f16* __restrict__ Wt,
    const float* __restrict__ bq, const float* __restrict__ bk,
    f16* __restrict__ qb, f16* __restrict__ kb) {
  GEMM_PRE();
  const int row0 = blockIdx.x * 128, col0 = blockIdx.y * 128;
  mm_loop(Xb + (long)row0 * DX, Wt + (long)col0 * DX, DX, DX, DX, lA, lB, acc);
  EPI_IDX();
#pragma unroll
  for (int n = 0; n < 4; ++n) {
    int col = col0 + wc + n * 16 + fr;
    float bias = (col < DE) ? bq[col] : bk[col - DE];
    f16* op = (col < DE) ? (qb + col) : (kb + col - DE);
#pragma unroll
    for (int m = 0; m < 4; ++m)
#pragma unroll
      for (int r = 0; r < 4; ++r) {
        int row = row0 + wr + m * 16 + fq * 4 + r;
        op[(long)row * DE] = (f16)(acc[m][n][r] + bias);
      }
  }
}

// V transposed: Vt[d][token] = sum_k Wv[k][d]*X[token][k] + bv[d]; M=1024, N=16384
__global__ __launch_bounds__(256) void gemm_vt_kernel(
    const f16* __restrict__ WtV, const f16* __restrict__ Xb,
    const float* __restrict__ bv, f16* __restrict__ Vt) {
  GEMM_PRE();
  const int row0 = blockIdx.x * 128, col0 = blockIdx.y * 128;
  mm_loop(WtV + (long)row0 * DX, Xb + (long)col0 * DX, DX, DX, DX, lA, lB, acc);
  EPI_IDX();
#pragma unroll
  for (int n = 0; n < 4; ++n) {
    int col = col0 + wc + n * 16 + fr;
#pragma unroll
    for (int m = 0; m < 4; ++m)
#pragma unroll
      for (int r = 0; r < 4; ++r) {
        int row = row0 + wr + m * 16 + fq * 4 + r;
        Vt[(long)row * NT + col] = (f16)(acc[m][n][r] + bv[row]);
      }
  }
}

// per-batch scores: S = (q.k * 1/32) * (m.m) * (l_i*l_j), fp32 out [4096][4096]
__global__ __launch_bounds__(256) void gemm_scores_kernel(
    const f16* __restrict__ qb, const f16* __restrict__ kb,
    const f16* __restrict__ mb, const float* __restrict__ l,
    float* __restrict__ S) {
  __shared__ __attribute__((aligned(16))) f16 lA[128 * 32], lB[128 * 32];
  f32x4 acc[4][4], am[4][4];
#pragma unroll
  for (int m = 0; m < 4; ++m)
#pragma unroll
    for (int n = 0; n < 4; ++n) {
      acc[m][n] = (f32x4){0.f, 0.f, 0.f, 0.f};
      am[m][n] = (f32x4){0.f, 0.f, 0.f, 0.f};
    }
  const int row0 = blockIdx.x * 128, col0 = blockIdx.y * 128;
  mm_loop(qb + (long)row0 * DE, kb + (long)col0 * DE, DE, DE, DE, lA, lB, acc);
  mm_loop(mb + (long)row0 * DM, mb + (long)col0 * DM, DM, DM, DM, lA, lB, am);
  EPI_IDX();
  const float scale = 0.03125f;
#pragma unroll
  for (int n = 0; n < 4; ++n) {
    int col = col0 + wc + n * 16 + fr;
    float lc = l[col];
#pragma unroll
    for (int m = 0; m < 4; ++m)
#pragma unroll
      for (int r = 0; r < 4; ++r) {
        int row = row0 + wr + m * 16 + fq * 4 + r;
        S[(long)row * NN + col] = acc[m][n][r] * scale * am[m][n][r] * l[row] * lc;
      }
  }
}

// row softmax: S fp32 [4096] -> P f16, one block per row
__global__ __launch_bounds__(256) void softmax_kernel(const float* __restrict__ S,
                                                      f16* __restrict__ P) {
  __shared__ float red[8];
  const long row = blockIdx.x;
  const float* s = S + row * NN;
  const int t = threadIdx.x;
  float4 v[4];
  float mx = -3.0e38f;
#pragma unroll
  for (int i = 0; i < 4; ++i) {
    v[i] = *(const float4*)(s + t * 4 + i * 1024);
    mx = fmaxf(mx, fmaxf(fmaxf(v[i].x, v[i].y), fmaxf(v[i].z, v[i].w)));
  }
#pragma unroll
  for (int o = 32; o; o >>= 1) mx = fmaxf(mx, __shfl_xor(mx, o));
  if ((t & 63) == 0) red[t >> 6] = mx;
  __syncthreads();
  mx = fmaxf(fmaxf(red[0], red[1]), fmaxf(red[2], red[3]));
  float sum = 0.f;
#pragma unroll
  for (int i = 0; i < 4; ++i) {
    v[i].x = __expf(v[i].x - mx); v[i].y = __expf(v[i].y - mx);
    v[i].z = __expf(v[i].z - mx); v[i].w = __expf(v[i].w - mx);
    sum += v[i].x + v[i].y + v[i].z + v[i].w;
  }
#pragma unroll
  for (int o = 32; o; o >>= 1) sum += __shfl_xor(sum, o);
  if ((t & 63) == 0) red[4 + (t >> 6)] = sum;
  __syncthreads();
  float inv = 1.f / (red[4] + red[5] + red[6] + red[7]);
  f16* p = P + row * NN;
#pragma unroll
  for (int i = 0; i < 4; ++i) {
    f16x4 o4 = { (f16)(v[i].x * inv), (f16)(v[i].y * inv),
                 (f16)(v[i].z * inv), (f16)(v[i].w * inv) };
    *(f16x4*)(p + t * 4 + i * 1024) = o4;
  }
}

// h = P @ V (K=4096), fused residual: outE = e + h, outH = h. grid (32,8,4)
__global__ __launch_bounds__(256) void gemm_pv_kernel(
    const f16* __restrict__ P, const f16* __restrict__ Vt,
    const float* __restrict__ e, float* __restrict__ outE, float* __restrict__ outH) {
  GEMM_PRE();
  const int b = blockIdx.z;
  const int row0 = blockIdx.x * 128, col0 = blockIdx.y * 128;
  const f16* A = P + (long)b * NN * NN + (long)row0 * NN;
  const f16* B = Vt + (long)col0 * NT + (long)b * NN;
  mm_loop(A, B, NN, NT, NN, lA, lB, acc);
  EPI_IDX();
#pragma unroll
  for (int n = 0; n < 4; ++n) {
    int col = col0 + wc + n * 16 + fr;
#pragma unroll
    for (int m = 0; m < 4; ++m)
#pragma unroll
      for (int r = 0; r < 4; ++r) {
        int row = row0 + wr + m * 16 + fq * 4 + r;
        long idx = ((long)b * NN + row) * DE + col;
        float h = acc[m][n][r];
        outE[idx] = e[idx] + h;
        outH[idx] = h;
      }
  }
}

extern "C" void kernel_launch(void* const* d_in, const int* in_sizes, int n_in,
                              void* d_out, int out_size, void* d_ws, size_t ws_size,
                              hipStream_t stream) {
  const float* e  = (const float*)d_in[0];
  const float* m  = (const float*)d_in[1];
  const float* c  = (const float*)d_in[2];
  const float* l  = (const float*)d_in[3];
  const float* Wq = (const float*)d_in[4];
  const float* bq = (const float*)d_in[5];
  const float* Wk = (const float*)d_in[6];
  const float* bk = (const float*)d_in[7];
  const float* Wv = (const float*)d_in[8];
  const float* bv = (const float*)d_in[9];
  float* outE = (float*)d_out;
  float* outH = outE + (long)NT * DE;

  char* ws = (char*)d_ws;
  size_t off = 0;
  auto alloc = [&](size_t bytes) {
    char* p = ws + off;
    off += (bytes + 255) & ~(size_t)255;
    return p;
  };
  f16* Xb    = (f16*)alloc((size_t)NT * DX * 2);
  f16* WtQK  = (f16*)alloc((size_t)2048 * DX * 2);
  f16* WtV   = (f16*)alloc((size_t)DE * DX * 2);
  f16* qb    = (f16*)alloc((size_t)NT * DE * 2);
  f16* kb    = (f16*)alloc((size_t)NT * DE * 2);
  f16* Vt    = (f16*)alloc((size_t)DE * NT * 2);
  f16* mb    = (f16*)alloc((size_t)NT * DM * 2);
  float* S   = (float*)alloc((size_t)NN * NN * 4);
  f16* P     = (f16*)alloc((size_t)NB * NN * NN * 2);
  if (off > ws_size) return;  // workspace too small -> will show as absmax fail

  build_x_kernel<<<2048, 256, 0, stream>>>(e, c, Xb);
  conv_f16_kernel<<<512, 256, 0, stream>>>(m, mb, NT * DM / 4);
  transpose_w_kernel<<<dim3(32, 36), dim3(32, 8), 0, stream>>>(Wq, WtQK);
  transpose_w_kernel<<<dim3(32, 36), dim3(32, 8), 0, stream>>>(Wk, WtQK + (size_t)DE * DX);
  transpose_w_kernel<<<dim3(32, 36), dim3(32, 8), 0, stream>>>(Wv, WtV);
  gemm_qk_kernel<<<dim3(128, 16), 256, 0, stream>>>(Xb, WtQK, bq, bk, qb, kb);
  gemm_vt_kernel<<<dim3(8, 128), 256, 0, stream>>>(WtV, Xb, bv, Vt);
  for (int b = 0; b < NB; ++b) {
    gemm_scores_kernel<<<dim3(32, 32), 256, 0, stream>>>(
        qb + (size_t)b * NN * DE, kb + (size_t)b * NN * DE,
        mb + (size_t)b * NN * DM, l + (size_t)b * NN, S);
    softmax_kernel<<<NN, 256, 0, stream>>>(S, P + (size_t)b * NN * NN);
  }
  gemm_pv_kernel<<<dim3(32, 8, NB), 256, 0, stream>>>(P, Vt, e, outE, outH);
}

// Round 2
// 676.539 us; speedup vs baseline: 1.1790x; 1.1790x over previous
//
#include <hip/hip_runtime.h>
#include <hip/hip_bf16.h>

#define DE 1024
#define DM 64
#define DC 128
#define DX 1152      // DE+DC
#define NB 4
#define NN 4096
#define NT 16384     // NB*NN

typedef _Float16 f16;
typedef _Float16 f16x4 __attribute__((ext_vector_type(4)));
typedef _Float16 f16x8 __attribute__((ext_vector_type(8)));
typedef float f32x4 __attribute__((ext_vector_type(4)));

__device__ __forceinline__ void g2l16(const void* g, void* l) {
  __builtin_amdgcn_global_load_lds(
      (const __attribute__((address_space(1))) unsigned int*)(unsigned long long)g,
      (__attribute__((address_space(3))) unsigned int*)(unsigned int)(unsigned long long)l,
      16, 0, 0);
}

#define MEMF() asm volatile("" ::: "memory")
#define BAR() { MEMF(); __builtin_amdgcn_s_barrier(); MEMF(); }

// ---------------- prep kernels ----------------
__global__ void build_x_kernel(const float* __restrict__ e, const float* __restrict__ c,
                               f16* __restrict__ Xb) {
  const int total = NT * DX / 4;
  for (int i = blockIdx.x * blockDim.x + threadIdx.x; i < total; i += gridDim.x * blockDim.x) {
    int idx = i * 4;
    int r = idx / DX, col = idx - r * DX;
    float4 v;
    if (col < DE) v = *(const float4*)(e + (long)r * DE + col);
    else          v = *(const float4*)(c + (long)r * DC + (col - DE));
    f16x4 o = { (f16)v.x, (f16)v.y, (f16)v.z, (f16)v.w };
    *(f16x4*)(Xb + (long)idx) = o;
  }
}

__global__ void conv_f16_kernel(const float* __restrict__ in, f16* __restrict__ out, int total4) {
  for (int i = blockIdx.x * blockDim.x + threadIdx.x; i < total4; i += gridDim.x * blockDim.x) {
    float4 v = *(const float4*)(in + (long)i * 4);
    f16x4 o = { (f16)v.x, (f16)v.y, (f16)v.z, (f16)v.w };
    *(f16x4*)(out + (long)i * 4) = o;
  }
}

// in [DX][DE] f32  ->  out [DE][DX] f16
__global__ void transpose_w_kernel(const float* __restrict__ in, f16* __restrict__ out) {
  __shared__ float tile[32][33];
  int c0 = blockIdx.x * 32, r0 = blockIdx.y * 32;
  int x = threadIdx.x, y = threadIdx.y;   // block (32,8)
#pragma unroll
  for (int i = 0; i < 4; ++i)
    tile[y + 8 * i][x] = in[(long)(r0 + y + 8 * i) * DE + (c0 + x)];
  __syncthreads();
#pragma unroll
  for (int i = 0; i < 4; ++i)
    out[(long)(c0 + y + 8 * i) * DX + (r0 + x)] = (f16)tile[x][y + 8 * i];
}

// ---------------- legacy 128^2 GEMM core (for the small mask GEMM, K=64) -----
__device__ __forceinline__ void mm_loop(const f16* __restrict__ A, const f16* __restrict__ B,
                                        int lda, int ldb, int K,
                                        f16* lA, f16* lB, f32x4 (&acc)[4][4]) {
  const int t = threadIdx.x;
  const int lane = t & 63;
  const int wid = t >> 6;
  const int wr = (wid >> 1) * 64, wc = (wid & 1) * 64;
  const int fr = lane & 15, fq = lane >> 4;
  for (int k0 = 0; k0 < K; k0 += 32) {
    __syncthreads();
#pragma unroll
    for (int it = 0; it < 2; ++it) {
      int byteoff = it * 4096 + t * 16;
      int row = byteoff >> 6;
      int ke = (byteoff & 63) >> 1;
      g2l16(A + (long)row * lda + k0 + ke, lA + (byteoff >> 1));
      g2l16(B + (long)row * ldb + k0 + ke, lB + (byteoff >> 1));
    }
    __syncthreads();
    f16x8 af[4], bfr[4];
#pragma unroll
    for (int i = 0; i < 4; ++i) {
      af[i]  = *(const f16x8*)(lA + (wr + i * 16 + fr) * 32 + fq * 8);
      bfr[i] = *(const f16x8*)(lB + (wc + i * 16 + fr) * 32 + fq * 8);
    }
#pragma unroll
    for (int m = 0; m < 4; ++m)
#pragma unroll
      for (int n = 0; n < 4; ++n)
        acc[m][n] = __builtin_amdgcn_mfma_f32_16x16x32_f16(af[m], bfr[n], acc[m][n], 0, 0, 0);
  }
}

// Pmask[b][i][j] = (m_i . m_j) * l_i * l_j / 32   (f16), grid (32,32,4)
__global__ __launch_bounds__(256) void mask_kernel(
    const f16* __restrict__ mb, const float* __restrict__ l, f16* __restrict__ Pm) {
  __shared__ __attribute__((aligned(16))) f16 lA[128 * 32], lB[128 * 32];
  f32x4 acc[4][4];
#pragma unroll
  for (int m = 0; m < 4; ++m)
#pragma unroll
    for (int n = 0; n < 4; ++n) acc[m][n] = (f32x4){0.f, 0.f, 0.f, 0.f};
  const int b = blockIdx.z;
  const int row0 = blockIdx.x * 128, col0 = blockIdx.y * 128;
  mm_loop(mb + (long)(b * NN + row0) * DM, mb + (long)(b * NN + col0) * DM,
          DM, DM, DM, lA, lB, acc);
  const int lane = threadIdx.x & 63, wid = threadIdx.x >> 6;
  const int wr = (wid >> 1) * 64, wc = (wid & 1) * 64;
  const int fr = lane & 15, fq = lane >> 4;
  const float* lb = l + (long)b * NN;
  f16* out = Pm + (long)b * NN * NN;
#pragma unroll
  for (int n = 0; n < 4; ++n) {
    int col = col0 + wc + n * 16 + fr;
    float lc = lb[col] * 0.03125f;
#pragma unroll
    for (int m = 0; m < 4; ++m)
#pragma unroll
      for (int r = 0; r < 4; ++r) {
        int row = row0 + wr + m * 16 + fq * 4 + r;
        out[(long)row * NN + col] = (f16)(acc[m][n][r] * lc * lb[row]);
      }
  }
}

// ---------------- 256^2 8-phase GEMM core ----------------
// C[256x256] = A[256xK] * B[256xK]^T ; 512 threads = 8 waves (2M x 4N),
// per-wave 128x64 out = acc[8][4] of 16x16x32 f16 MFMA.
// LDS: A/B tiles 256x64 f16 (32KB each), double-buffered = 128KB, linear dest
// for global_load_lds; bank-conflict-free ds_read via source-side XOR swizzle
// (LDS byte bits 4-6 ^= row&7; on reads this collapses to a per-lane const).
__device__ __forceinline__ void gemm8_core(
    const f16* __restrict__ A, long lda,
    const f16* __restrict__ B, long ldb,
    int NTt, char* ldsb, f32x4 (&acc)[8][4]) {
  const int tid = threadIdx.x;
  const int lane = tid & 63, wid = tid >> 6;
  const int wr = wid >> 2, wc = wid & 3;
  const int fr = lane & 15, fq = lane >> 4;
  const int cb0 = ((fq) ^ (fr & 7)) << 4;        // ks=0 byte col offset (swizzled)
  const int cb1 = ((4 | fq) ^ (fr & 7)) << 4;    // ks=1

  // stage one 16KB piece; pc selects the rows read in P1 (pc=0) / P3|P2 (pc=1)
  auto stageA = [&](int pc, int kt, int par) {
    char* base = ldsb + par * 32768;
    int k0 = kt * 64;
#pragma unroll
    for (int it = 0; it < 2; ++it) {
      int p = it * 8192 + tid * 16;
      int off = pc * 8192 + ((p >> 13) << 14) + (p & 8191);
      int sw = off ^ (((off >> 7) & 7) << 4);
      int row = sw >> 7;
      int colf = ((sw >> 4) & 7) << 3;
      g2l16(A + (long)row * lda + k0 + colf, base + off);
    }
  };
  auto stageB = [&](int pc, int kt, int par) {
    char* base = ldsb + 65536 + par * 32768;
    int k0 = kt * 64;
#pragma unroll
    for (int it = 0; it < 2; ++it) {
      int p = it * 8192 + tid * 16;
      int off = pc * 4096 + ((p >> 12) << 13) + (p & 4095);
      int sw = off ^ (((off >> 7) & 7) << 4);
      int row = sw >> 7;
      int colf = ((sw >> 4) & 7) << 3;
      g2l16(B + (long)row * ldb + k0 + colf, base + off);
    }
  };

  f16x8 af[4][2], bf0[2][2], bf1[2][2];
  auto rdA = [&](int mh, int par) {
    const char* base = ldsb + par * 32768;
#pragma unroll
    for (int i = 0; i < 4; ++i) {
      int row = wr * 128 + mh * 64 + i * 16 + fr;
      af[i][0] = *(const f16x8*)(const void*)(base + row * 128 + cb0);
      af[i][1] = *(const f16x8*)(const void*)(base + row * 128 + cb1);
    }
  };
  auto rdB = [&](f16x8 (&bf)[2][2], int nh, int par) {
    const char* base = ldsb + 65536 + par * 32768;
#pragma unroll
    for (int i = 0; i < 2; ++i) {
      int row = wc * 64 + nh * 32 + i * 16 + fr;
      bf[i][0] = *(const f16x8*)(const void*)(base + row * 128 + cb0);
      bf[i][1] = *(const f16x8*)(const void*)(base + row * 128 + cb1);
    }
  };
  auto mma = [&](f16x8 (&bf)[2][2], int mo, int no) {
    __builtin_amdgcn_s_setprio(1);
#pragma unroll
    for (int m = 0; m < 4; ++m)
#pragma unroll
      for (int n = 0; n < 2; ++n)
#pragma unroll
        for (int k = 0; k < 2; ++k)
          acc[mo + m][no + n] =
              __builtin_amdgcn_mfma_f32_16x16x32_f16(af[m][k], bf[n][k], acc[mo + m][no + n], 0, 0, 0);
    __builtin_amdgcn_s_setprio(0);
  };

  MEMF();
  // prologue: tile0 (4 pieces) + tile1 (first 3 pieces)
  stageA(0, 0, 0); stageB(0, 0, 0); stageA(1, 0, 0); stageB(1, 0, 0);
  stageA(0, 1, 1); stageB(0, 1, 1); stageA(1, 1, 1);
  asm volatile("s_waitcnt vmcnt(6)" ::: "memory");
  BAR();

  for (int t = 0; t < NTt; t += 2) {
#pragma unroll
    for (int half = 0; half < 2; ++half) {
      const int tt = t + half;
      const int par = half, npar = half ^ 1;
      // P1: read A-p0 + B-p0; stage [t+1 : B-p1]
      rdA(0, par); rdB(bf0, 0, par);
      if (tt + 1 < NTt) stageB(1, tt + 1, npar);
      BAR();
      mma(bf0, 0, 0);
      BAR();
      // P2: read B-p1; stage [t+2 : A-p0]
      rdB(bf1, 1, par);
      if (tt + 2 < NTt) stageA(0, tt + 2, par);
      BAR();
      mma(bf1, 0, 2);
      BAR();
      // P3: read A-p1; stage [t+2 : B-p0]
      rdA(1, par);
      if (tt + 2 < NTt) stageB(0, tt + 2, par);
      BAR();
      mma(bf1, 4, 2);
      BAR();
      // P4: stage [t+2 : A-p1]; mma; counted drain before next tile
      if (tt + 2 < NTt) stageA(1, tt + 2, par);
      BAR();
      mma(bf0, 4, 0);
      if (tt + 1 < NTt) {
        if (tt + 1 == NTt - 1) { asm volatile("s_waitcnt vmcnt(0)" ::: "memory"); }
        else                   { asm volatile("s_waitcnt vmcnt(6)" ::: "memory"); }
      }
      BAR();
    }
  }
  MEMF();
}

__device__ __forceinline__ void swz_grid(int& bx, int& by, int& bz) {
  int nx = gridDim.x, ny = gridDim.y;
  int flat = blockIdx.x + nx * (blockIdx.y + ny * blockIdx.z);
  int total = nx * ny * gridDim.z;
  int cpx = total >> 3;               // all grids are multiples of 8
  flat = (flat & 7) * cpx + (flat >> 3);
  bx = flat % nx; int r = flat / nx;
  by = r % ny; bz = r / ny;
}

#define ACC_INIT()                                                  \
  f32x4 acc[8][4];                                                  \
  _Pragma("unroll") for (int m_ = 0; m_ < 8; ++m_)                  \
  _Pragma("unroll") for (int n_ = 0; n_ < 4; ++n_)                  \
      acc[m_][n_] = (f32x4){0.f, 0.f, 0.f, 0.f};

#define EPI8_IDX()                                                  \
  const int lane = threadIdx.x & 63, wid = threadIdx.x >> 6;        \
  const int wr = wid >> 2, wc = wid & 3;                            \
  const int fr = lane & 15, fq = lane >> 4;

// q,k projection: M=16384, N=2048 (q|k), K=1152. grid (64,8)
__global__ __launch_bounds__(512, 2) void qk8_kernel(
    const f16* __restrict__ Xb, const f16* __restrict__ Wt,
    const float* __restrict__ bq, const float* __restrict__ bk,
    f16* __restrict__ qb, f16* __restrict__ kb) {
  __shared__ __attribute__((aligned(128))) char ldsb[131072];
  int bx, by, bz; swz_grid(bx, by, bz);
  const int row0 = bx * 256, col0 = by * 256;
  ACC_INIT();
  gemm8_core(Xb + (long)row0 * DX, DX, Wt + (long)col0 * DX, DX, DX / 64, ldsb, acc);
  EPI8_IDX();
  const bool isq = col0 < DE;
  const float* bvec = isq ? bq : bk;
  f16* ob = isq ? qb : kb;
  const int cbase = (isq ? col0 : col0 - DE) + wc * 64;
  const int rbase = row0 + wr * 128;
#pragma unroll
  for (int n = 0; n < 4; ++n) {
    int col = cbase + n * 16 + fr;
    float bb = bvec[col];
#pragma unroll
    for (int m = 0; m < 8; ++m)
#pragma unroll
      for (int j = 0; j < 4; ++j) {
        int row = rbase + m * 16 + fq * 4 + j;
        ob[(long)row * DE + col] = (f16)(acc[m][n][j] + bb);
      }
  }
}

// Vt[d][token]: M=1024 (d), N=16384 (tokens), K=1152. grid (4,64)
__global__ __launch_bounds__(512, 2) void vt8_kernel(
    const f16* __restrict__ WtV, const f16* __restrict__ Xb,
    const float* __restrict__ bv, f16* __restrict__ Vt) {
  __shared__ __attribute__((aligned(128))) char ldsb[131072];
  int bx, by, bz; swz_grid(bx, by, bz);
  const int row0 = bx * 256, col0 = by * 256;
  ACC_INIT();
  gemm8_core(WtV + (long)row0 * DX, DX, Xb + (long)col0 * DX, DX, DX / 64, ldsb, acc);
  EPI8_IDX();
  const int cbase = col0 + wc * 64;
  const int rbase = row0 + wr * 128;
#pragma unroll
  for (int n = 0; n < 4; ++n) {
    int col = cbase + n * 16 + fr;
#pragma unroll
    for (int m = 0; m < 8; ++m)
#pragma unroll
      for (int j = 0; j < 4; ++j) {
        int row = rbase + m * 16 + fq * 4 + j;
        Vt[(long)row * NT + col] = (f16)(acc[m][n][j] + bv[row]);
      }
  }
}

// raw scores per batch: S = q.k (fp32). grid (16,16)
__global__ __launch_bounds__(512, 2) void sc8_kernel(
    const f16* __restrict__ qb_, const f16* __restrict__ kb_, float* __restrict__ S) {
  __shared__ __attribute__((aligned(128))) char ldsb[131072];
  int bx, by, bz; swz_grid(bx, by, bz);
  const int row0 = bx * 256, col0 = by * 256;
  ACC_INIT();
  gemm8_core(qb_ + (long)row0 * DE, DE, kb_ + (long)col0 * DE, DE, DE / 64, ldsb, acc);
  EPI8_IDX();
  const int cbase = col0 + wc * 64;
  const int rbase = row0 + wr * 128;
#pragma unroll
  for (int n = 0; n < 4; ++n) {
    int col = cbase + n * 16 + fr;
#pragma unroll
    for (int m = 0; m < 8; ++m)
#pragma unroll
      for (int j = 0; j < 4; ++j) {
        int row = rbase + m * 16 + fq * 4 + j;
        S[(long)row * NN + col] = acc[m][n][j];
      }
  }
}

// h = P @ V (K=4096); outE = e + h, outH = h. grid (16,4,4)
__global__ __launch_bounds__(512, 2) void pv8_kernel(
    const f16* __restrict__ P, const f16* __restrict__ Vt,
    const float* __restrict__ e, float* __restrict__ outE, float* __restrict__ outH) {
  __shared__ __attribute__((aligned(128))) char ldsb[131072];
  int bx, by, bz; swz_grid(bx, by, bz);
  const int b = bz;
  const int row0 = bx * 256, col0 = by * 256;
  ACC_INIT();
  gemm8_core(P + (long)b * NN * NN + (long)row0 * NN, NN,
             Vt + (long)col0 * NT + (long)b * NN, NT, NN / 64, ldsb, acc);
  EPI8_IDX();
  const int cbase = col0 + wc * 64;
  const int rbase = row0 + wr * 128;
#pragma unroll
  for (int n = 0; n < 4; ++n) {
    int col = cbase + n * 16 + fr;
#pragma unroll
    for (int m = 0; m < 8; ++m)
#pragma unroll
      for (int j = 0; j < 4; ++j) {
        int row = rbase + m * 16 + fq * 4 + j;
        long idx = ((long)b * NN + row) * DE + col;
        float h = acc[m][n][j];
        outE[idx] = e[idx] + h;
        outH[idx] = h;
      }
  }
}

// row softmax with mask: v = S * Pm -> softmax -> P (f16, in-place over Pm)
__global__ __launch_bounds__(256) void softmax_kernel(const float* __restrict__ S,
                                                      const f16* __restrict__ Pm,
                                                      f16* __restrict__ P) {
  __shared__ float red[8];
  const long row = blockIdx.x;
  const float* s = S + row * NN;
  const f16* pmr = Pm + row * NN;
  const int t = threadIdx.x;
  float4 v[4];
  float mx = -3.0e38f;
#pragma unroll
  for (int i = 0; i < 4; ++i) {
    v[i] = *(const float4*)(s + t * 4 + i * 1024);
    f16x4 m4 = *(const f16x4*)(pmr + t * 4 + i * 1024);
    v[i].x *= (float)m4[0]; v[i].y *= (float)m4[1];
    v[i].z *= (float)m4[2]; v[i].w *= (float)m4[3];
    mx = fmaxf(mx, fmaxf(fmaxf(v[i].x, v[i].y), fmaxf(v[i].z, v[i].w)));
  }
#pragma unroll
  for (int o = 32; o; o >>= 1) mx = fmaxf(mx, __shfl_xor(mx, o));
  if ((t & 63) == 0) red[t >> 6] = mx;
  __syncthreads();
  mx = fmaxf(fmaxf(red[0], red[1]), fmaxf(red[2], red[3]));
  float sum = 0.f;
#pragma unroll
  for (int i = 0; i < 4; ++i) {
    v[i].x = __expf(v[i].x - mx); v[i].y = __expf(v[i].y - mx);
    v[i].z = __expf(v[i].z - mx); v[i].w = __expf(v[i].w - mx);
    sum += v[i].x + v[i].y + v[i].z + v[i].w;
  }
#pragma unroll
  for (int o = 32; o; o >>= 1) sum += __shfl_xor(sum, o);
  if ((t & 63) == 0) red[4 + (t >> 6)] = sum;
  __syncthreads();
  float inv = 1.f / (red[4] + red[5] + red[6] + red[7]);
  f16* p = P + row * NN;
#pragma unroll
  for (int i = 0; i < 4; ++i) {
    f16x4 o4 = { (f16)(v[i].x * inv), (f16)(v[i].y * inv),
                 (f16)(v[i].z * inv), (f16)(v[i].w * inv) };
    *(f16x4*)(p + t * 4 + i * 1024) = o4;
  }
}

extern "C" void kernel_launch(void* const* d_in, const int* in_sizes, int n_in,
                              void* d_out, int out_size, void* d_ws, size_t ws_size,
                              hipStream_t stream) {
  const float* e  = (const float*)d_in[0];
  const float* m  = (const float*)d_in[1];
  const float* c  = (const float*)d_in[2];
  const float* l  = (const float*)d_in[3];
  const float* Wq = (const float*)d_in[4];
  const float* bq = (const float*)d_in[5];
  const float* Wk = (const float*)d_in[6];
  const float* bk = (const float*)d_in[7];
  const float* Wv = (const float*)d_in[8];
  const float* bv = (const float*)d_in[9];
  float* outE = (float*)d_out;
  float* outH = outE + (long)NT * DE;

  char* ws = (char*)d_ws;
  size_t off = 0;
  auto alloc = [&](size_t bytes) {
    char* p = ws + off;
    off += (bytes + 255) & ~(size_t)255;
    return p;
  };
  f16* Xb    = (f16*)alloc((size_t)NT * DX * 2);
  f16* WtQK  = (f16*)alloc((size_t)2048 * DX * 2);
  f16* WtV   = (f16*)alloc((size_t)DE * DX * 2);
  f16* qb    = (f16*)alloc((size_t)NT * DE * 2);
  f16* kb    = (f16*)alloc((size_t)NT * DE * 2);
  f16* Vt    = (f16*)alloc((size_t)DE * NT * 2);
  f16* mb    = (f16*)alloc((size_t)NT * DM * 2);
  float* S   = (float*)alloc((size_t)NN * NN * 4);
  f16* P     = (f16*)alloc((size_t)NB * NN * NN * 2);  // Pmask aliases P (consumed in-place)
  if (off > ws_size) return;

  build_x_kernel<<<2048, 256, 0, stream>>>(e, c, Xb);
  conv_f16_kernel<<<512, 256, 0, stream>>>(m, mb, NT * DM / 4);
  transpose_w_kernel<<<dim3(32, 36), dim3(32, 8), 0, stream>>>(Wq, WtQK);
  transpose_w_kernel<<<dim3(32, 36), dim3(32, 8), 0, stream>>>(Wk, WtQK + (size_t)DE * DX);
  transpose_w_kernel<<<dim3(32, 36), dim3(32, 8), 0, stream>>>(Wv, WtV);
  mask_kernel<<<dim3(32, 32, NB), 256, 0, stream>>>(mb, l, P);
  qk8_kernel<<<dim3(64, 8), 512, 0, stream>>>(Xb, WtQK, bq, bk, qb, kb);
  vt8_kernel<<<dim3(4, 64), 512, 0, stream>>>(WtV, Xb, bv, Vt);
  for (int b = 0; b < NB; ++b) {
    sc8_kernel<<<dim3(16, 16), 512, 0, stream>>>(
        qb + (size_t)b * NN * DE, kb + (size_t)b * NN * DE, S);
    softmax_kernel<<<NN, 256, 0, stream>>>(S, P + (size_t)b * NN * NN, P + (size_t)b * NN * NN);
  }
  pv8_kernel<<<dim3(16, 4, NB), 512, 0, stream>>>(P, Vt, e, outE, outH);
}